// Round 1
// 79.885 us; speedup vs baseline: 1.0191x; 1.0191x over previous
//
#include <hip/hip_runtime.h>
#include <math.h>

#define BEV_H 200
#define BEV_W 200
#define NPIX (BEV_H * BEV_W)
#define TILE 8
#define NT 25           // 200/8
#define NB 2
#define T_DEAD 1e-10f
#define SEGCAP 512      // per-wave segment capacity (G/4 = 500)
#define PCAP 128        // params parked at scan time (multiple of KC)
#define KC 32           // feature-staging chunk per wave
#define NLOG255 (-5.5412635f)   // -ln(255)
#define GSTRIDE 2048    // padded per-batch gaussian stride in workspace

// workspace layout (bytes from d_ws base; all 16B-aligned)
#define WS_PPA 0                              // float4[NB*GSTRIDE]   65536
#define WS_PPB (WS_PPA + NB * GSTRIDE * 16)   // float2[NB*GSTRIDE]   32768
#define WS_BND (WS_PPB + NB * GSTRIDE * 8)    // u32   [NB*GSTRIDE]   16384
#define WS_PF  (WS_BND + NB * GSTRIDE * 4)    // uint4 [NB*GSTRIDE*4] 262144
// total 376832 B << ws_size

// round-to-nearest bf16 pack of two floats into one uint (lo=x, hi=y)
__device__ __forceinline__ unsigned pk2bf(float x, float y)
{
    unsigned ux = __float_as_uint(x), uy = __float_as_uint(y);
    ux = ux + 0x7fffu + ((ux >> 16) & 1u);
    uy = uy + 0x7fffu + ((uy >> 16) & 1u);
    return (ux >> 16) | (uy & 0xffff0000u);
}

// R13 prep: per-gaussian precompute, ONCE instead of once-per-tile (1250x).
//  - conic params (identical formulas to R12's inline scan -> bit-identical)
//  - conservative tile bbox via the EXACT same squared interval test R12
//    used (25+25 tests), packed as 4x u8 -> keep-set provably identical
//  - bf16-packed feature quads (same pk2bf -> bit-identical staging data)
// Invalid gaussians (op<=0.05 || det<=0 || g>=G) get ti0=255 -> never kept.
__global__ __launch_bounds__(256) void prep_kernel(
    const float* __restrict__ features, const float* __restrict__ means3D,
    const float* __restrict__ cov3D, const float* __restrict__ opac,
    float4* __restrict__ ppA, float2* __restrict__ ppB,
    unsigned* __restrict__ bnd, uint4* __restrict__ pf, int G)
{
    const int t = blockIdx.x * 256 + threadIdx.x;   // 64 blocks x 256 = 16384

    // ---- job A: params + tile bounds, t in [0, NB*GSTRIDE) ----
    if (t < NB * GSTRIDE) {
        const int b = t >> 11;               // GSTRIDE = 2048
        const int g = t & (GSTRIDE - 1);
        unsigned bd = 0x000000FFu;           // ti0=255 -> empty range
        if (g < G) {
            const size_t gi = (size_t)(b * G + g);
            const float x = means3D[gi * 3 + 0], y = means3D[gi * 3 + 1];
            const float s0 = cov3D[gi * 6 + 0], s1 = cov3D[gi * 6 + 1],
                        s3 = cov3D[gi * 6 + 3];
            const float op = opac[gi];
            const float u = -2.0f * y + 100.0f;   // sh = BEV_H/H_METERS = 2
            const float v = -2.0f * x + 100.0f;
            const float c00 = 4.0f * s3 + 0.3f;
            const float c01 = 4.0f * s1;
            const float c11 = 4.0f * s0 + 0.3f;
            const float det = c00 * c11 - c01 * c01;
            if (op > 0.05f && det > 0.0f) {
                const float L = __logf(255.0f * op);       // > 0 since op > 0.05
                const float Au = 2.0f * L * c00 + 1e-4f;
                const float Av = 2.0f * L * c11 + 1e-4f;
                int ti0 = 255, ti1 = 0, tj0 = 255, tj1 = 0;
                // exact replication of R12's per-tile squared test
                for (int tt = 0; tt < NT; ++tt) {
                    const float lo = (float)(tt * TILE), hi = lo + (TILE - 1);
                    const float dut = fmaxf(fmaxf(lo - u, u - hi), 0.0f);
                    const float dvt = fmaxf(fmaxf(lo - v, v - hi), 0.0f);
                    if (dut * dut <= Au) { if (tt < ti0) ti0 = tt; ti1 = tt; }
                    if (dvt * dvt <= Av) { if (tt < tj0) tj0 = tt; tj1 = tt; }
                }
                const float inv = 1.0f / det;
                ppA[t] = make_float4(u, v, -0.5f * c11 * inv, c01 * inv);
                ppB[t] = make_float2(-0.5f * c00 * inv, L + NLOG255);
                bd = (unsigned)ti0 | ((unsigned)ti1 << 8) |
                     ((unsigned)tj0 << 16) | ((unsigned)tj1 << 24);
            }
        }
        bnd[t] = bd;
    }

    // ---- job B: bf16 feature pack, one quarter (8 floats) per thread ----
    if (t < NB * G * 4) {                    // 16000 quarters
        const int q = t & 3;
        const int gg = t >> 2;               // [0, NB*G)
        const int b = (gg >= G) ? 1 : 0;     // NB == 2
        const int g = gg - b * G;
        const float4* fp = (const float4*)(features + (size_t)gg * 32) + q * 2;
        const float4 A = fp[0], Bq = fp[1];
        pf[(size_t)(b * GSTRIDE + g) * 4 + q] =
            make_uint4(pk2bf(A.x, A.y), pk2bf(A.z, A.w),
                       pk2bf(Bq.x, Bq.y), pk2bf(Bq.z, Bq.w));
    }
}

// R13 render (= R12 with the scan's per-gaussian math/loads replaced by a
// coalesced 4-B bounds read + integer range test, params fetched from the
// prep arrays, and feature staging reading pre-packed bf16 quads):
//  - 4 waves per 8x8 tile, G in 4 segments (compositing monoid:
//    out = a0 + T0*a1 + T0T1*a2 + T0T1T2*a3).
//  - scan: all 8 rounds' bounds preloaded up-front (no latency chain).
//  - composite: branchless, bf16 features in LDS (unchanged).
//  - combine: GUARD barrier + PUBLISH barrier (unchanged from R12).
//  - count folded into block 0 wave 1 post-barrier (unchanged).
__global__ __launch_bounds__(256, 5) void render_fused_kernel(
    const float* __restrict__ opac,
    const float4* __restrict__ ppA, const float2* __restrict__ ppB,
    const unsigned* __restrict__ bndg, const uint4* __restrict__ pf,
    float* __restrict__ out, int G)
{
    // glist u16[4][512] @0 (4096) | plA f4[4][128] @4096 (8192) |
    // plB f2[4][128] @12288 (4096) | flq u4[4][32][4] @16384 (8192) = 24576 B
    // combine overlay (GUARD-barrier-protected): xch f32[3][64][17] @0 (13056)
    __shared__ __align__(16) unsigned char smem[24576];
    unsigned short* glist = (unsigned short*)smem;
    float4* plA = (float4*)(smem + 4096);
    float2* plB = (float2*)(smem + 12288);
    uint4*  flq = (uint4*)(smem + 16384);
    float*  xch = (float*)smem;

    const int tid  = threadIdx.x;
    const int lane = tid & 63;
    const int w    = tid >> 6;           // wave id = G-segment id
    const int b  = blockIdx.z;
    const int tj = blockIdx.x;
    const int ti = blockIdx.y;
    const int j = tj * TILE + (lane & 7);
    const int i = ti * TILE + (lane >> 3);
    const float fi = (float)i, fj = (float)j;
    const int g_lo = (w * G) >> 2;
    const int g_hi = ((w + 1) * G) >> 2;
    const int pbase0 = b * GSTRIDE;

    // ---- scan: coalesced bounds reads, integer test, ballot compaction ----
    int tot = 0;
    {
        unsigned bv[8];                       // 500 gaussians -> 8 rounds
        const unsigned* bb = bndg + pbase0 + g_lo;
#pragma unroll
        for (int r = 0; r < 8; ++r)           // max index 1500+448+63 = 2011 < 2048
            bv[r] = bb[r * 64 + lane];
#pragma unroll
        for (int r = 0; r < 8; ++r) {
            const int g = g_lo + r * 64 + lane;
            const unsigned bd = bv[r];
            const bool keep = (g < g_hi) &&
                (ti >= (int)(bd & 255u)) && (ti <= (int)((bd >> 8) & 255u)) &&
                (tj >= (int)((bd >> 16) & 255u)) && (tj <= (int)(bd >> 24));
            const unsigned long long bal = __ballot(keep);
            if (keep) {
                const int slot = tot + (int)__popcll(bal & ((1ull << lane) - 1ull));
                glist[w * SEGCAP + slot] = (unsigned short)g;
                if (slot < PCAP) {
                    plA[w * PCAP + slot] = ppA[pbase0 + g];
                    plB[w * PCAP + slot] = ppB[pbase0 + g];
                }
            }
            tot += (int)__popcll(bal);
        }
    }

    // ---- wave-local: stage packed features per chunk + branchless composite ----
    float acc[32];
#pragma unroll
    for (int d = 0; d < 32; ++d) acc[d] = 0.0f;
    float T = 1.0f;   // within-segment transmittance

    for (int k0 = 0; k0 < tot; k0 += KC) {
        if (!__any(T >= T_DEAD)) break;
        const int nk = min(KC, tot - k0);

        // overflow chunks (k0 >= PCAP; ~never at ~11 kept/wave): fetch params
        // from prep arrays into slots [0,KC)
        if (k0 >= PCAP && lane < nk) {
            const int g = glist[w * SEGCAP + k0 + lane];
            plA[w * PCAP + lane] = ppA[pbase0 + g];
            plB[w * PCAP + lane] = ppB[pbase0 + g];
        }
        // stage pre-packed bf16 features: entry e, quarter q (one uint4 each)
        for (int idx = lane; idx < nk * 4; idx += 64) {
            const int e = idx >> 2, q = idx & 3;
            const int g = glist[w * SEGCAP + k0 + e];
            flq[(w * KC + e) * 4 + q] = pf[(size_t)(pbase0 + g) * 4 + q];
        }
        // same-wave LDS ordering: compiler inserts lgkmcnt waits

        const int pbase = w * PCAP + ((k0 < PCAP) ? k0 : 0);
        for (int k = 0; k < nk; ++k) {
            const float4 pA = plA[pbase + k];
            const float2 pB = plB[pbase + k];
            const float du = pA.x - fi;
            const float dv = pA.y - fj;
            const float power = pA.z * du * du + pB.x * dv * dv + pA.w * du * dv;
            const float powb = power + pB.y;          // + ln(op)
            float alpha = fminf(0.99f, __expf(powb));
            const bool ok = (powb >= NLOG255) && (power <= 0.0f);
            alpha = ok ? alpha : 0.0f;
            const float wgt = alpha * T;
            T *= 1.0f - alpha;
#pragma unroll
            for (int q = 0; q < 4; ++q) {
                const uint4 uq = flq[(w * KC + k) * 4 + q];
                const unsigned uu[4] = {uq.x, uq.y, uq.z, uq.w};
#pragma unroll
                for (int c = 0; c < 4; ++c) {
                    const float lof = __uint_as_float(uu[c] << 16);
                    const float hif = __uint_as_float(uu[c] & 0xffff0000u);
                    acc[q * 8 + c * 2 + 0] = fmaf(wgt, lof, acc[q * 8 + c * 2 + 0]);
                    acc[q * 8 + c * 2 + 1] = fmaf(wgt, hif, acc[q * 8 + c * 2 + 1]);
                }
            }
        }
    }

    // ---- combine: GUARD barrier, publish partials, PUBLISH barrier ----
    __syncthreads();   // guard: all waves done reading glist/plA/plB/flq
    if (w != 0) {
        float* row = xch + ((w - 1) * 64 + lane) * 17;
        unsigned* urow = (unsigned*)row;
#pragma unroll
        for (int c2 = 0; c2 < 16; ++c2)
            urow[c2] = pk2bf(acc[2 * c2], acc[2 * c2 + 1]);
        row[16] = T;
    }
    __syncthreads();   // publish

    if (w == 0) {
        float W = T;   // running prefix transmittance T0, T0T1, T0T1T2
#pragma unroll
        for (int r = 1; r <= 3; ++r) {
            const float* row = xch + ((r - 1) * 64 + lane) * 17;
            const unsigned* urow = (const unsigned*)row;
#pragma unroll
            for (int c2 = 0; c2 < 16; ++c2) {
                const unsigned uv = urow[c2];
                acc[2 * c2 + 0] = fmaf(W, __uint_as_float(uv << 16),
                                       acc[2 * c2 + 0]);
                acc[2 * c2 + 1] = fmaf(W, __uint_as_float(uv & 0xffff0000u),
                                       acc[2 * c2 + 1]);
            }
            W *= row[16];
        }

        const int p = i * BEV_W + j;   // 200 % 8 == 0: always in range
        float* ob = out + (size_t)b * 32 * NPIX + p;
#pragma unroll
        for (int d = 0; d < 32; ++d) ob[(size_t)d * NPIX] = acc[d];
    }

    // ---- num_gaussians = sum(op > 0.05)/B on block 0 wave 1 (hidden tail) ----
    if (w == 1 && blockIdx.x == 0 && blockIdx.y == 0 && blockIdx.z == 0) {
        const float4* o4 = (const float4*)opac;
        const int n4 = (NB * G) >> 2;
        float s = 0.0f;
        for (int idx = lane; idx < n4; idx += 64) {
            const float4 o = o4[idx];
            s += (o.x > 0.05f ? 1.0f : 0.0f) + (o.y > 0.05f ? 1.0f : 0.0f) +
                 (o.z > 0.05f ? 1.0f : 0.0f) + (o.w > 0.05f ? 1.0f : 0.0f);
        }
#pragma unroll
        for (int off = 32; off > 0; off >>= 1) s += __shfl_down(s, off);
        if (lane == 0) out[NB * 32 * NPIX] = s * (1.0f / NB);
    }
}

extern "C" void kernel_launch(void* const* d_in, const int* in_sizes, int n_in,
                              void* d_out, int out_size, void* d_ws, size_t ws_size,
                              hipStream_t stream)
{
    const float* features = (const float*)d_in[0];
    const float* means3D  = (const float*)d_in[1];
    const float* cov3D    = (const float*)d_in[2];
    const float* opac     = (const float*)d_in[3];
    float* out = (float*)d_out;

    const int G = in_sizes[3] / NB;   // opacities is (B, G, 1)

    char* ws = (char*)d_ws;
    float4*   ppA = (float4*)(ws + WS_PPA);
    float2*   ppB = (float2*)(ws + WS_PPB);
    unsigned* bnd = (unsigned*)(ws + WS_BND);
    uint4*    pf  = (uint4*)(ws + WS_PF);

    prep_kernel<<<64, 256, 0, stream>>>(features, means3D, cov3D, opac,
                                        ppA, ppB, bnd, pf, G);

    dim3 grid(NT, NT, NB);
    render_fused_kernel<<<grid, 256, 0, stream>>>(opac, ppA, ppB, bnd, pf,
                                                  out, G);
}